// Round 7
// baseline (408.882 us; speedup 1.0000x reference)
//
#include <hip/hip_runtime.h>
#include <hip/hip_bf16.h>

// Problem constants (BS=2, SLEN=2048, DIM=2048, H=16, DH=128)
// I/O dtype: fp32. Internals: bf16 MFMA, fp32 accumulation, bf16 workspace.
#define S_LEN 2048
#define DIMN  2048
#define NHEAD 16
#define DHEAD 128
#define SEGQ  ((size_t)4096 * 2048)
#define SEGW  ((size_t)2048 * 2048)

typedef __attribute__((ext_vector_type(8))) short short8;
typedef __attribute__((ext_vector_type(4))) float floatx4;

__device__ inline float bf2f(unsigned short u) {
    union { unsigned int i; float f; } v; v.i = ((unsigned int)u) << 16; return v.f;
}
__device__ inline unsigned short f2bf(float f) {
    unsigned int x = __float_as_uint(f);
    unsigned int r = (x + 0x7FFFu + ((x >> 16) & 1u)) >> 16;  // RNE
    return (unsigned short)r;
}
__device__ inline short8 ld8_f32_as_bf16(const float* p) {
    float4 a = *(const float4*)p;
    float4 b = *(const float4*)(p + 4);
    short8 r;
    r[0] = (short)f2bf(a.x); r[1] = (short)f2bf(a.y);
    r[2] = (short)f2bf(a.z); r[3] = (short)f2bf(a.w);
    r[4] = (short)f2bf(b.x); r[5] = (short)f2bf(b.y);
    r[6] = (short)f2bf(b.z); r[7] = (short)f2bf(b.w);
    return r;
}
// Async global->LDS, 16B/lane; LDS base wave-uniform, lane i at +i*16.
__device__ inline void glds16(unsigned short* lds, const unsigned short* g) {
    __builtin_amdgcn_global_load_lds(
        (const __attribute__((address_space(1))) unsigned int*)g,
        (__attribute__((address_space(3))) unsigned int*)lds, 16, 0, 0);
}

// Raw barrier with scheduler fences (no vmcnt/lgkmcnt drain — HK/m201 pattern)
#define SBAR() do { __builtin_amdgcn_sched_barrier(0); \
                    __builtin_amdgcn_s_barrier();      \
                    __builtin_amdgcn_sched_barrier(0); } while (0)

// ---------------------------------------------------------------------------
// One-shot fp32 -> bf16 conversion of x, Wq, Wk, Wv, Wo (blockIdx.y selects).
// ---------------------------------------------------------------------------
__global__ __launch_bounds__(256) void cvt5_kernel(
    const float* __restrict__ s0, const float* __restrict__ s1,
    const float* __restrict__ s2, const float* __restrict__ s3,
    const float* __restrict__ s4,
    unsigned short* __restrict__ d0, unsigned short* __restrict__ d1,
    unsigned short* __restrict__ d2, unsigned short* __restrict__ d3,
    unsigned short* __restrict__ d4)
{
    const float* s; unsigned short* d; size_t n;
    switch (blockIdx.y) {
        case 0:  s = s0; d = d0; n = SEGQ; break;
        case 1:  s = s1; d = d1; n = SEGW; break;
        case 2:  s = s2; d = d2; n = SEGW; break;
        case 3:  s = s3; d = d3; n = SEGW; break;
        default: s = s4; d = d4; n = SEGW; break;
    }
    size_t stride = (size_t)gridDim.x * 256 * 8;
    for (size_t i = ((size_t)blockIdx.x * 256 + threadIdx.x) * 8; i < n; i += stride)
        *(short8*)&d[i] = ld8_f32_as_bf16(&s[i]);
}

// ---------------------------------------------------------------------------
// gemm3 (R2-verified): counted-vmcnt 3-buffer pipelined GEMM. FROZEN.
//   BM=256, BN=128, BK=32, 512 thr = 8 waves (4M x 2N), 64x64 per wave.
//   Journal: R3 (128x64 waves, 4-wave blocks) = 169 us, R5 (8-phase 256^2
//   lockstep) = 158 us -- both LOST to this 141-159 us structure. Do not
//   re-attempt GEMM structure transfer without new counter evidence.
// EPI=0: fused QKV epilogue with in-epilogue L2 norm (n-tile = one head).
// EPI=1: fp32 flat output + bias.
// ---------------------------------------------------------------------------
#define BUFE (384 * 32)   // elements per buffer: A 256x32 + B 128x32

template <int EPI>
__global__ __launch_bounds__(512) void gemm3(
    const unsigned short* __restrict__ A, const unsigned short* __restrict__ Bw,
    const float* __restrict__ b0, const float* __restrict__ b1,
    const float* __restrict__ b2, const float* __restrict__ scale_p,
    void* __restrict__ Cp, int M, int N, int K)
{
    __shared__ __align__(16) unsigned short sBuf[3 * BUFE];   // 73728 B

    const int tid  = threadIdx.x;
    const int w    = tid >> 6, lane = tid & 63;
    const int l15  = lane & 15, quad = lane >> 4;
    const int wr   = w >> 1, wc = w & 1;            // 4M x 2N waves
    const int tm   = blockIdx.y * 256, tn = blockIdx.x * 128;

    const int colE = ((lane & 3) * 8) ^ (((lane >> 3) & 3) << 3);
    const int cs   = (quad * 8) ^ (((l15 >> 1) & 3) << 3);
    const int srow = w * 16 + (lane >> 2);          // 0..127 staging row

    floatx4 acc[4][4] = {};

    auto stage = [&](int kt, int bsel) {
        const int k0 = kt * 32;
        glds16(&sBuf[bsel * BUFE + 0 * 4096 + w * 512],
               &A[(size_t)(tm + srow) * K + k0 + colE]);
        glds16(&sBuf[bsel * BUFE + 1 * 4096 + w * 512],
               &A[(size_t)(tm + 128 + srow) * K + k0 + colE]);
        glds16(&sBuf[bsel * BUFE + 8192 + w * 512],
               &Bw[(size_t)(tn + srow) * K + k0 + colE]);
    };

    const int nT = K >> 5;            // 64 K-tiles
    stage(0, 0);
    stage(1, 1);

    int bs = 0;
    for (int t = 0; t < nT; ++t) {
        if (t < nT - 1) asm volatile("s_waitcnt vmcnt(3)" ::: "memory");
        else            asm volatile("s_waitcnt vmcnt(0)" ::: "memory");
        __builtin_amdgcn_s_barrier();
        __builtin_amdgcn_sched_barrier(0);

        const unsigned short* bufA = &sBuf[bs * BUFE];
        const unsigned short* bufB = bufA + 8192;
        short8 af[4], bfr[4];
#pragma unroll
        for (int mi = 0; mi < 4; mi++)
            af[mi] = *(const short8*)&bufA[(wr * 64 + mi * 16 + l15) * 32 + cs];
#pragma unroll
        for (int ni = 0; ni < 4; ni++)
            bfr[ni] = *(const short8*)&bufB[(wc * 64 + ni * 16 + l15) * 32 + cs];

        if (t + 2 < nT) stage(t + 2, bs == 0 ? 2 : bs - 1);

        __builtin_amdgcn_s_setprio(1);
#pragma unroll
        for (int mi = 0; mi < 4; mi++)
#pragma unroll
            for (int ni = 0; ni < 4; ni++)
                acc[mi][ni] = __builtin_amdgcn_mfma_f32_16x16x32_bf16(af[mi], bfr[ni], acc[mi][ni], 0, 0, 0);
        __builtin_amdgcn_s_setprio(0);

        bs = (bs == 2) ? 0 : bs + 1;
    }
    __syncthreads();   // loop done, nothing outstanding; safe full drain

    // Epilogue: C/D layout row = quad*4 + r, col = l15 (m89-verified)
    if (EPI == 0) {
        const int t = tn >> 11;
        const float* bp = (t == 0) ? b0 : (t == 1) ? b1 : b2;
        unsigned short* Q = (unsigned short*)Cp;
        // bias first (reference normalizes x@W.T + b)
#pragma unroll
        for (int ni = 0; ni < 4; ni++) {
            int n = tn + wc * 64 + ni * 16 + l15;
            float bias = bp[n & 2047];
#pragma unroll
            for (int mi = 0; mi < 4; mi++)
#pragma unroll
                for (int r = 0; r < 4; r++) acc[mi][ni][r] += bias;
        }
        // per-row sum of squares over this wave's 64-dh half
        float ssq[4][4];
#pragma unroll
        for (int mi = 0; mi < 4; mi++)
#pragma unroll
            for (int r = 0; r < 4; r++) {
                float s = 0.0f;
#pragma unroll
                for (int ni = 0; ni < 4; ni++) s += acc[mi][ni][r] * acc[mi][ni][r];
#pragma unroll
                for (int off = 1; off < 16; off <<= 1) s += __shfl_xor(s, off, 64);
                ssq[mi][r] = s;
            }
        float* ssh = (float*)sBuf;      // 512 floats, reuse sBuf
        if (l15 == 0) {
#pragma unroll
            for (int mi = 0; mi < 4; mi++)
#pragma unroll
                for (int r = 0; r < 4; r++)
                    ssh[wc * 256 + wr * 64 + mi * 16 + quad * 4 + r] = ssq[mi][r];
        }
        __syncthreads();
        const float scl = (t == 0) ? scale_p[0] : 1.0f;
#pragma unroll
        for (int mi = 0; mi < 4; mi++) {
            int mbase = tm + wr * 64 + mi * 16 + quad * 4;
#pragma unroll
            for (int r = 0; r < 4; r++) {
                float tot = ssq[mi][r] + ssh[(wc ^ 1) * 256 + wr * 64 + mi * 16 + quad * 4 + r];
                float f = (t < 2) ? rsqrtf(tot) * scl : 1.0f;
                int m = mbase + r;
                int b = m >> 11, s = m & 2047;
#pragma unroll
                for (int ni = 0; ni < 4; ni++) {
                    int n = tn + wc * 64 + ni * 16 + l15;
                    int h = (n >> 7) & 15, dh = n & 127;
                    float v = acc[mi][ni][r] * f;
                    size_t idx = (t < 2)
                        ? (size_t)t * SEGQ + (((size_t)(b * NHEAD + h)) * S_LEN + s) * DHEAD + dh
                        : 2 * SEGQ + (((size_t)(b * NHEAD + h)) * DHEAD + dh) * S_LEN + s;
                    Q[idx] = f2bf(v);
                }
            }
        }
    } else {
#pragma unroll
        for (int mi = 0; mi < 4; mi++) {
            int mbase = tm + wr * 64 + mi * 16 + quad * 4;
#pragma unroll
            for (int ni = 0; ni < 4; ni++) {
                int n = tn + wc * 64 + ni * 16 + l15;
                float bias = b0[n];
#pragma unroll
                for (int r = 0; r < 4; r++) {
                    int m = mbase + r;
                    ((float*)Cp)[(size_t)m * N + n] = acc[mi][ni][r] + bias;
                }
            }
        }
    }
}

// ---------------------------------------------------------------------------
// Fallback GEMM: fp32 A/B converted during staging.
// SPLIT: 0 none, 1 (b,h,s,dh), 2 transposed V (b,h,dh,s).
// ---------------------------------------------------------------------------
template <int SPLIT, int A_F32, int OUT_F32>
__global__ __launch_bounds__(256) void gemm_bt(
    const void* __restrict__ Ap, const float* __restrict__ Bw,
    const float* __restrict__ bias, void* __restrict__ Cp,
    int M, int N, int K)
{
    __shared__ __align__(16) unsigned short sA[128 * 40];
    __shared__ __align__(16) unsigned short sB[128 * 40];

    const int tid  = threadIdx.x;
    const int w    = tid >> 6, lane = tid & 63;
    const int l15  = lane & 15, quad = lane >> 4;
    const int wm   = w >> 1, wn = w & 1;
    const int tm   = blockIdx.y * 128, tn = blockIdx.x * 128;

    const float*          Af32 = (const float*)Ap;
    const unsigned short* Abf  = (const unsigned short*)Ap;

    floatx4 acc[4][4] = {};

    for (int k0 = 0; k0 < K; k0 += 32) {
        __syncthreads();
#pragma unroll
        for (int i = 0; i < 2; i++) {
            int c   = tid + i * 256;
            int row = c >> 2;
            int kc  = (c & 3) * 8;
            size_t goff = (size_t)(tm + row) * K + k0 + kc;
            if (A_F32)
                *(short8*)&sA[row * 40 + kc] = ld8_f32_as_bf16(&Af32[goff]);
            else
                *(short8*)&sA[row * 40 + kc] = *(const short8*)&Abf[goff];
            *(short8*)&sB[row * 40 + kc] =
                ld8_f32_as_bf16(&Bw[(size_t)(tn + row) * K + k0 + kc]);
        }
        __syncthreads();

        short8 af[4], bfr[4];
#pragma unroll
        for (int mi = 0; mi < 4; mi++)
            af[mi] = *(const short8*)&sA[(wm * 64 + mi * 16 + l15) * 40 + quad * 8];
#pragma unroll
        for (int ni = 0; ni < 4; ni++)
            bfr[ni] = *(const short8*)&sB[(wn * 64 + ni * 16 + l15) * 40 + quad * 8];
#pragma unroll
        for (int mi = 0; mi < 4; mi++)
#pragma unroll
            for (int ni = 0; ni < 4; ni++)
                acc[mi][ni] = __builtin_amdgcn_mfma_f32_16x16x32_bf16(af[mi], bfr[ni], acc[mi][ni], 0, 0, 0);
    }

#pragma unroll
    for (int mi = 0; mi < 4; mi++) {
        int mbase = tm + wm * 64 + mi * 16 + quad * 4;
#pragma unroll
        for (int ni = 0; ni < 4; ni++) {
            int n = tn + wn * 64 + ni * 16 + l15;
            float bv = bias[n];
#pragma unroll
            for (int r = 0; r < 4; r++) {
                int m = mbase + r;
                float v = acc[mi][ni][r] + bv;
                if (SPLIT == 1) {
                    int b = m >> 11, s = m & 2047, h = n >> 7, dh = n & 127;
                    ((unsigned short*)Cp)[(((size_t)(b * NHEAD + h)) * S_LEN + s) * DHEAD + dh] = f2bf(v);
                } else if (SPLIT == 2) {
                    int b = m >> 11, s = m & 2047, h = n >> 7, dh = n & 127;
                    ((unsigned short*)Cp)[(((size_t)(b * NHEAD + h)) * DHEAD + dh) * S_LEN + s] = f2bf(v);
                } else if (OUT_F32) {
                    ((float*)Cp)[(size_t)m * N + n] = v;
                } else {
                    ((unsigned short*)Cp)[(size_t)m * N + n] = f2bf(v);
                }
            }
        }
    }
}

// ---------------------------------------------------------------------------
// Fallback-path L2 norm (fast path fuses it into the QKV epilogue).
// ---------------------------------------------------------------------------
__global__ __launch_bounds__(256) void l2norm_kernel(
    unsigned short* __restrict__ qn, unsigned short* __restrict__ kn,
    const float* __restrict__ scale_p)
{
    const int w = threadIdx.x >> 6, lane = threadIdx.x & 63;
    size_t row = (size_t)blockIdx.x * 4 + w;
    unsigned short* base = (blockIdx.y == 0 ? qn : kn) + row * DHEAD;
    float a = bf2f(base[lane * 2]);
    float b = bf2f(base[lane * 2 + 1]);
    float ss = a * a + b * b;
#pragma unroll
    for (int off = 1; off < 64; off <<= 1) ss += __shfl_xor(ss, off, 64);
    float f = rsqrtf(ss);
    if (blockIdx.y == 0) f *= scale_p[0];
    base[lane * 2]     = f2bf(a * f);
    base[lane * 2 + 1] = f2bf(b * f);
}

// ---------------------------------------------------------------------------
// Flash attention v6: v5 structure + two R6 fixes.
//  A. RAW BARRIERS, no vmcnt drain in loop. v5's __syncthreads() after the
//     prefetch compiled to s_waitcnt vmcnt(0) -> every iter synchronously
//     waited for the just-issued K/V prefetch (the m97-stall). Now:
//       SBAR();            // WAR: all waves' ds_reads were consumed by
//                          // MFMAs before reaching here (lgkmcnt implicit)
//       commit kpre/vpre   // ds_writes; compiler auto-waits the targeted
//                          // vmcnt for last iter's loads (already landed)
//       prefetch next      // global loads stay in flight across barriers
//       lgkmcnt(0); SBAR();// RAW: my ds_writes visible to all waves
//  B. 4-bit XOR bank swizzle (both-sides involution, rule #21):
//     phys_elem = col ^ ((row&15)<<3), stride 128 elems (256 B, no pad).
//     b128 reads previously landed 16 lanes on 4 of 8 bank-windows (2x over
//     uniform); swizzle spreads them uniformly (8 lanes/window = b128 min).
//     Applied identically at commit-write and all reads (sK, sVt, sP).
// Kept from v5: wave-private sP (no softmax->PV barrier), setprio on MFMA
// clusters, XCD remap (4 heads/XCD = 4 MB K/V = one L2).
// LDS: 3 x 32 KB = 96 KB -> 1 block/CU.
// ---------------------------------------------------------------------------
__global__ __launch_bounds__(512) void attn_kernel6(
    const unsigned short* __restrict__ qn, const unsigned short* __restrict__ kn,
    const unsigned short* __restrict__ vt, unsigned short* __restrict__ ctx)
{
    __shared__ __align__(16) unsigned short sK [128 * 128];
    __shared__ __align__(16) unsigned short sVt[128 * 128];
    __shared__ __align__(16) unsigned short sP [8 * 16 * 128];

    const int tid  = threadIdx.x;
    const int w    = tid >> 6, lane = tid & 63;   // w in [0,8)
    const int l15  = lane & 15, quad = lane >> 4;
    const int lin  = blockIdx.x + (blockIdx.y << 3);
    const int xb   = (lin >> 3) & 7;
    const int bh   = ((lin & 7) << 2) | (lin >> 6);
    const size_t headoff = (size_t)bh * S_LEN * DHEAD;
    const unsigned short* kbase0 = kn + headoff;
    const unsigned short* vtbase = vt + headoff;   // [dh][s] within head
    unsigned short* sPw = sP + w * 16 * 128;

    short8 kpre[4], vpre[4];

    for (int half = 0; half < 2; half++) {
        const int qt = half ? (15 - xb) : xb;      // 128-row Q tiles

        const unsigned short* qrow = qn + headoff + (size_t)(qt * 128 + w * 16 + l15) * DHEAD;
        short8 aQ[4];
#pragma unroll
        for (int ks = 0; ks < 4; ks++) aQ[ks] = *(const short8*)(qrow + ks * 32 + quad * 8);

        floatx4 O[8] = {};
        float m_i[4], l_i[4];
#pragma unroll
        for (int r = 0; r < 4; r++) { m_i[r] = -1e30f; l_i[r] = 0.0f; }

        if (half == 0) {  // prefetch kt=0 (half 1 gets it from half 0's tail)
#pragma unroll
            for (int j = 0; j < 4; j++) {
                int c = tid + j * 512;   // 128x128 tile = 2048 16B chunks
                kpre[j] = *(const short8*)(kbase0 + (size_t)(c >> 4) * DHEAD + (c & 15) * 8);
                vpre[j] = *(const short8*)(vtbase + (size_t)(c >> 4) * S_LEN + (c & 15) * 8);
            }
        }

        for (int kt = 0; kt <= qt; kt++) {
            SBAR();   // WAR: previous iteration's LDS reads all consumed

            // Commit prefetched K/V (ds_write_b128, swizzled slot)
#pragma unroll
            for (int j = 0; j < 4; j++) {
                int c = tid + j * 512;
                int row = c >> 4;
                int sl  = (c & 15) ^ (row & 15);
                *(short8*)&sK [row * 128 + sl * 8] = kpre[j];
                *(short8*)&sVt[row * 128 + sl * 8] = vpre[j];
            }

            // Prefetch next tile (stays in flight across the barrier below)
            if (kt < qt || half == 0) {
                const int knext = (kt < qt) ? (kt + 1) * 128 : 0;
#pragma unroll
                for (int j = 0; j < 4; j++) {
                    int c = tid + j * 512;
                    kpre[j] = *(const short8*)(kbase0 + (size_t)(knext + (c >> 4)) * DHEAD + (c & 15) * 8);
                    vpre[j] = *(const short8*)(vtbase + (size_t)(c >> 4) * S_LEN + knext + (c & 15) * 8);
                }
            }
            asm volatile("s_waitcnt lgkmcnt(0)" ::: "memory");  // ds_writes visible
            SBAR();   // RAW: all waves' commits visible; vmcnt NOT drained

            // S = Q K^T (wave strip 16 x 128)
            floatx4 sc[8] = {};
            __builtin_amdgcn_s_setprio(1);
#pragma unroll
            for (int ks = 0; ks < 4; ks++) {
#pragma unroll
                for (int ni = 0; ni < 8; ni++) {
                    short8 bK = *(const short8*)&sK[(ni * 16 + l15) * 128 + (((ks * 4 + quad) ^ l15) * 8)];
                    sc[ni] = __builtin_amdgcn_mfma_f32_16x16x32_bf16(aQ[ks], bK, sc[ni], 0, 0, 0);
                }
            }
            __builtin_amdgcn_s_setprio(0);

            if (kt == qt) {  // causal mask within diagonal tile
#pragma unroll
                for (int ni = 0; ni < 8; ni++) {
                    int cl = ni * 16 + l15;
#pragma unroll
                    for (int r = 0; r < 4; r++) {
                        int rl = w * 16 + quad * 4 + r;
                        if (cl > rl) sc[ni][r] = -1e30f;
                    }
                }
            }

            // Online softmax (stats replicated across the 16 lanes of a quad)
            float rmax[4];
#pragma unroll
            for (int r = 0; r < 4; r++) {
                float mx = sc[0][r];
#pragma unroll
                for (int ni = 1; ni < 8; ni++) mx = fmaxf(mx, sc[ni][r]);
                rmax[r] = mx;
            }
#pragma unroll
            for (int off = 1; off < 16; off <<= 1)
#pragma unroll
                for (int r = 0; r < 4; r++) rmax[r] = fmaxf(rmax[r], __shfl_xor(rmax[r], off, 64));

            float alpha[4], rsum[4];
#pragma unroll
            for (int r = 0; r < 4; r++) {
                float mn = fmaxf(m_i[r], rmax[r]);
                alpha[r] = exp2f((m_i[r] - mn) * 1.44269504f);
                m_i[r] = mn;
                rsum[r] = 0.0f;
            }
#pragma unroll
            for (int ni = 0; ni < 8; ni++) {
#pragma unroll
                for (int r = 0; r < 4; r++) {
                    float p = exp2f((sc[ni][r] - m_i[r]) * 1.44269504f);
                    rsum[r] += p;
                    int prow = quad * 4 + r;
                    sPw[prow * 128 + ((ni * 16 + l15) ^ ((prow & 15) << 3))] = f2bf(p);
                }
            }
#pragma unroll
            for (int off = 1; off < 16; off <<= 1)
#pragma unroll
                for (int r = 0; r < 4; r++) rsum[r] += __shfl_xor(rsum[r], off, 64);
#pragma unroll
            for (int r = 0; r < 4; r++) l_i[r] = l_i[r] * alpha[r] + rsum[r];
#pragma unroll
            for (int t = 0; t < 8; t++)
#pragma unroll
                for (int r = 0; r < 4; r++) O[t][r] *= alpha[r];

            // No barrier: sP traffic is wave-private; compiler lgkmcnt orders
            // this wave's P writes before its own aP reads below.

            // O += P V   (k-dim = 128 keys)
            __builtin_amdgcn_s_setprio(1);
#pragma unroll
            for (int ks2 = 0; ks2 < 4; ks2++) {
                short8 aP = *(const short8*)&sPw[l15 * 128 + ((ks2 * 32 + quad * 8) ^ (l15 << 3))];
#pragma unroll
                for (int t = 0; t < 8; t++) {
                    short8 bV = *(const short8*)&sVt[(t * 16 + l15) * 128 + (((ks2 * 4 + quad) ^ l15) * 8)];
                    O[t] = __builtin_amdgcn_mfma_f32_16x16x32_bf16(aP, bV, O[t], 0, 0, 0);
                }
            }
            __builtin_amdgcn_s_setprio(0);
        }

        // Epilogue: ctx[b, s, h*128 + dh] = O / l
        const int b = bh >> 4, h = bh & 15;
#pragma unroll
        for (int r = 0; r < 4; r++) {
            float inv = 1.0f / l_i[r];
            int srow = qt * 128 + w * 16 + quad * 4 + r;
            size_t rowoff = ((size_t)(b * S_LEN + srow)) * DIMN + h * DHEAD;
#pragma unroll
            for (int t = 0; t < 8; t++)
                ctx[rowoff + t * 16 + l15] = f2bf(O[t][r] * inv);
        }
    }
}

// ---------------------------------------------------------------------------
extern "C" void kernel_launch(void* const* d_in, const int* in_sizes, int n_in,
                              void* d_out, int out_size, void* d_ws, size_t ws_size,
                              hipStream_t stream)
{
    const float* x     = (const float*)d_in[0];
    // d_in[1] = causal mask (bool) — deterministic tril, masking hard-coded
    const float* Wq    = (const float*)d_in[2];
    const float* bq    = (const float*)d_in[3];
    const float* Wk    = (const float*)d_in[4];
    const float* bk    = (const float*)d_in[5];
    const float* Wv    = (const float*)d_in[6];
    const float* bv    = (const float*)d_in[7];
    const float* Wo    = (const float*)d_in[8];
    const float* bo    = (const float*)d_in[9];
    const float* scale = (const float*)d_in[10];

    const int M = 4096, N = 2048, K = 2048;
    float* out = (float*)d_out;
    const size_t need = (SEGQ + 4 * SEGW + 3 * SEGQ) * sizeof(unsigned short); // 100.7 MB

    if (ws_size >= need) {
        // Fast path: bf16 operands; pipelined fused QKV GEMM (+L2 norm).
        unsigned short* xb  = (unsigned short*)d_ws;   // ctx aliases xb (dead after QKV)
        unsigned short* wqb = xb  + SEGQ;              // wqb|wkb|wvb contiguous = fused B
        unsigned short* wkb = wqb + SEGW;
        unsigned short* wvb = wkb + SEGW;
        unsigned short* wob = wvb + SEGW;
        unsigned short* qn  = wob + SEGW;              // qn|kn|vt contiguous
        unsigned short* kn  = qn  + SEGQ;
        unsigned short* vtb = kn  + SEGQ;
        unsigned short* ctx = xb;

        cvt5_kernel<<<dim3(512, 5), 256, 0, stream>>>(x, Wq, Wk, Wv, Wo,
                                                      xb, wqb, wkb, wvb, wob);
        gemm3<0><<<dim3(48, 16), 512, 0, stream>>>(xb, wqb, bq, bk, bv, scale, qn, M, 6144, K);
        attn_kernel6<<<dim3(8, 32), 512, 0, stream>>>(qn, kn, vtb, ctx);
        gemm3<1><<<dim3(16, 16), 512, 0, stream>>>(ctx, wob, bo, nullptr, nullptr, nullptr, out, M, N, K);
    } else {
        // Fallback (67 MB): fp32 operands converted during staging.
        unsigned short* qn  = (unsigned short*)d_ws;
        unsigned short* kn  = qn + SEGQ;
        unsigned short* vtb = kn + SEGQ;
        unsigned short* ctx = vtb + SEGQ;

        gemm_bt<1, 1, 0><<<dim3(16, 32), 256, 0, stream>>>(x, Wq, bq, qn, M, N, K);
        gemm_bt<1, 1, 0><<<dim3(16, 32), 256, 0, stream>>>(x, Wk, bk, kn, M, N, K);
        gemm_bt<2, 1, 0><<<dim3(16, 32), 256, 0, stream>>>(x, Wv, bv, vtb, M, N, K);
        l2norm_kernel<<<dim3(16384, 2), 256, 0, stream>>>(qn, kn, scale);
        attn_kernel6<<<dim3(8, 32), 512, 0, stream>>>(qn, kn, vtb, ctx);
        gemm_bt<0, 0, 1><<<dim3(16, 32), 256, 0, stream>>>(ctx, Wo, bo, out, M, N, K);
    }
}